// Round 1
// baseline (141.212 us; speedup 1.0000x reference)
//
#include <hip/hip_runtime.h>
#include <math.h>

// ---- problem constants ----
#define HH 32
#define WW 32
#define CC 128
#define PPIX 13
#define RPIX 6
#define NPIX 169      // 13*13
#define G14 14
#define NG 196        // 14*14
#define NTOT 338      // 2*169
#define DIRATE_ 2
#define HS 16
#define WSz 16
#define CS 512
#define PREG 7
#define RREG 3
#define NREG 49
#define QH 128        // quantized spatial dim
#define MAIN_BLOCKS 2048   // 2*32*32 pixels
#define REG_BLOCKS 512     // 2*16*16 semantic pixels

__device__ __forceinline__ float block_max(float v, float* red) {
    const int tid = threadIdx.x;
    red[tid] = v; __syncthreads();
    #pragma unroll
    for (int s = 128; s > 0; s >>= 1) {
        if (tid < s) red[tid] = fmaxf(red[tid], red[tid + s]);
        __syncthreads();
    }
    float r = red[0]; __syncthreads();
    return r;
}

__device__ __forceinline__ float block_sum(float v, float* red) {
    const int tid = threadIdx.x;
    red[tid] = v; __syncthreads();
    #pragma unroll
    for (int s = 128; s > 0; s >>= 1) {
        if (tid < s) red[tid] += red[tid + s];
        __syncthreads();
    }
    float r = red[0]; __syncthreads();
    return r;
}

__global__ __launch_bounds__(256) void colorizer_fused(
    const float* __restrict__ feats_r0,
    const float* __restrict__ feats_r1,
    const float* __restrict__ feats_t,
    const float* __restrict__ quant_r0,
    const float* __restrict__ quant_r1,
    const float* __restrict__ feats_rs1,
    const float* __restrict__ feats_ts,
    float* __restrict__ out,         // [2,3,32,32]
    float* __restrict__ corr_out)    // [2,1,49,256]
{
    __shared__ float tvec[CS];       // main uses first 128; region uses all 512
    __shared__ float red[256];
    __shared__ float smG[NG];        // region path reuses as 196 partials
    __shared__ float smC1[NPIX];
    __shared__ float smV[NTOT];
    __shared__ float smQ0[3*NG];
    __shared__ float smQ1[3*NPIX];

    const int tid = threadIdx.x;

    if (blockIdx.x < MAIN_BLOCKS) {
        const int b   = blockIdx.x >> 10;
        const int pix = blockIdx.x & 1023;
        const int y = pix >> 5, x = pix & 31;

        const float* tb = feats_t + b*CC*HH*WW + pix;
        for (int c = tid; c < CC; c += 256) tvec[c] = tb[c*(HH*WW)];
        __syncthreads();

        // ---- coarse correlation (dilation 2), one tap per thread ----
        float dv = 0.f;
        if (tid < NPIX) {
            int i = tid / PPIX, j = tid % PPIX;
            int ys = y + (i - RPIX)*DIRATE_;
            int xs = x + (j - RPIX)*DIRATE_;
            if (ys >= 0 && ys < HH && xs >= 0 && xs < WW) {
                const float* r = feats_r0 + b*CC*HH*WW + ys*WW + xs;
                float a = 0.f;
                #pragma unroll 8
                for (int c = 0; c < CC; ++c) a = fmaf(tvec[c], r[c*(HH*WW)], a);
                dv = a;
            }
        }
        // softmax over 169 -> expected offset
        float m = block_max(tid < NPIX ? dv : -INFINITY, red);
        float e = (tid < NPIX) ? expf(dv - m) : 0.f;
        float gvj = (tid < NPIX) ? (float)(tid % PPIX - RPIX) : 0.f;
        float gvi = (tid < NPIX) ? (float)(tid / PPIX - RPIX) : 0.f;
        float ssum = block_sum(e, red);
        float sx = block_sum(e * gvj, red);
        float sy = block_sum(e * gvi, red);
        const float off_x = sx / ssum * (float)DIRATE_;
        const float off_y = sy / ssum * (float)DIRATE_;

        const float fy = (float)y + off_y, fx = (float)x + off_x;
        const float fly = floorf(fy), flx = floorf(fx);
        const int yb = (int)fly - RPIX, xb = (int)flx - RPIX;
        const float wy = fy - fly, wx = fx - flx;
        const float w00 = (1.f-wy)*(1.f-wx), w01 = (1.f-wy)*wx;
        const float w10 = wy*(1.f-wx),       w11 = wy*wx;

        // ---- 365 dots: 14x14 integer grid G on r0 + 13x13 corr1 on r1 ----
        for (int idx = tid; idx < NG + NPIX; idx += 256) {
            int ys, xs; const float* rb2; float* dst;
            if (idx < NG) {
                ys = yb + idx / G14; xs = xb + idx % G14;
                rb2 = feats_r0; dst = &smG[idx];
            } else {
                int k = idx - NG;
                ys = y + k / PPIX - RPIX; xs = x + k % PPIX - RPIX;
                rb2 = feats_r1; dst = &smC1[k];
            }
            float a = 0.f;
            if (ys >= 0 && ys < HH && xs >= 0 && xs < WW) {
                const float* r = rb2 + b*CC*HH*WW + ys*WW + xs;
                #pragma unroll 8
                for (int c = 0; c < CC; ++c) a = fmaf(tvec[c], r[c*(HH*WW)], a);
            }
            *dst = a;
        }
        // stage qr0 (14x14 grid, ::4 slice) and qr1 (13x13, ::4 slice), 3 channels
        for (int idx = tid; idx < 3*NG; idx += 256) {
            int ch = idx / NG, a2 = idx % NG;
            int ys = yb + a2 / G14, xs = xb + a2 % G14;
            smQ0[idx] = (ys>=0 && ys<HH && xs>=0 && xs<WW)
                        ? quant_r0[((b*3+ch)*QH + ys*4)*QH + xs*4] : 0.f;
        }
        for (int idx = tid; idx < 3*NPIX; idx += 256) {
            int ch = idx / NPIX, a2 = idx % NPIX;
            int ys = y + a2 / PPIX - RPIX, xs = x + a2 % PPIX - RPIX;
            smQ1[idx] = (ys>=0 && ys<HH && xs>=0 && xs<WW)
                        ? quant_r1[((b*3+ch)*QH + ys*4)*QH + xs*4] : 0.f;
        }
        __syncthreads();

        // ---- logits = concat(bilinear(G), corr1) ----
        for (int idx = tid; idx < NTOT; idx += 256) {
            float v;
            if (idx < NPIX) {
                int i = idx / PPIX, j = idx % PPIX;
                int g = i*G14 + j;
                v = w00*smG[g] + w01*smG[g+1] + w10*smG[g+G14] + w11*smG[g+G14+1];
            } else {
                v = smC1[idx - NPIX];
            }
            smV[idx] = v;
        }
        __syncthreads();

        // ---- fused softmax + (corr_pixel * image_uf).sum(n) ----
        float ml = -INFINITY;
        for (int idx = tid; idx < NTOT; idx += 256) ml = fmaxf(ml, smV[idx]);
        const float M = block_max(ml, red);
        float dpart = 0.f, o0 = 0.f, o1 = 0.f, o2 = 0.f;
        for (int idx = tid; idx < NTOT; idx += 256) {
            float ee = expf(smV[idx] - M);
            dpart += ee;
            if (idx < NPIX) {
                int i = idx / PPIX, j = idx % PPIX;
                int g = i*G14 + j;
                o0 += ee * (w00*smQ0[g]        + w01*smQ0[g+1]
                          + w10*smQ0[g+G14]    + w11*smQ0[g+G14+1]);
                o1 += ee * (w00*smQ0[NG+g]     + w01*smQ0[NG+g+1]
                          + w10*smQ0[NG+g+G14] + w11*smQ0[NG+g+G14+1]);
                o2 += ee * (w00*smQ0[2*NG+g]     + w01*smQ0[2*NG+g+1]
                          + w10*smQ0[2*NG+g+G14] + w11*smQ0[2*NG+g+G14+1]);
            } else {
                int k = idx - NPIX;
                o0 += ee * smQ1[k];
                o1 += ee * smQ1[NPIX + k];
                o2 += ee * smQ1[2*NPIX + k];
            }
        }
        const float denom = block_sum(dpart, red);
        o0 = block_sum(o0, red);
        o1 = block_sum(o1, red);
        o2 = block_sum(o2, red);
        if (tid == 0) {
            const float inv = 1.f / denom;
            out[((b*3+0)*HH + y)*WW + x] = o0 * inv;
            out[((b*3+1)*HH + y)*WW + x] = o1 * inv;
            out[((b*3+2)*HH + y)*WW + x] = o2 * inv;
        }
    } else {
        // ---- region correlation on semantic feats + softmax ----
        const int rb  = blockIdx.x - MAIN_BLOCKS;
        const int b   = rb >> 8;
        const int pix = rb & 255;
        const int y = pix >> 4, x = pix & 15;

        const float* tb = feats_ts + b*CS*HS*WSz + pix;
        for (int c = tid; c < CS; c += 256) tvec[c] = tb[c*(HS*WSz)];
        __syncthreads();

        float part = 0.f;
        if (tid < NREG*4) {
            int n = tid >> 2, p = tid & 3;
            int ys = y + n / PREG - RREG, xs = x + n % PREG - RREG;
            if (ys >= 0 && ys < HS && xs >= 0 && xs < WSz) {
                const float* r = feats_rs1 + b*CS*HS*WSz + ys*WSz + xs;
                const int c0 = p*128;
                #pragma unroll 8
                for (int c = c0; c < c0+128; ++c) part = fmaf(tvec[c], r[c*(HS*WSz)], part);
            }
        }
        if (tid < NREG*4) smG[tid] = part;
        __syncthreads();

        float val = 0.f;
        const bool act = tid < NREG;
        if (act) val = smG[tid*4] + smG[tid*4+1] + smG[tid*4+2] + smG[tid*4+3];
        const float M = block_max(act ? val : -INFINITY, red);
        const float e = act ? expf(val - M) : 0.f;
        const float s = block_sum(e, red);
        if (act) corr_out[b*NREG*(HS*WSz) + tid*(HS*WSz) + pix] = e / s;
    }
}

extern "C" void kernel_launch(void* const* d_in, const int* in_sizes, int n_in,
                              void* d_out, int out_size, void* d_ws, size_t ws_size,
                              hipStream_t stream) {
    const float* feats_r0 = (const float*)d_in[0];
    const float* feats_r1 = (const float*)d_in[1];
    const float* feats_t  = (const float*)d_in[2];
    const float* q_r0     = (const float*)d_in[3];
    const float* q_r1     = (const float*)d_in[4];
    // d_in[5] = feats_r_semantic0 (unused by reference)
    const float* rs1      = (const float*)d_in[6];
    const float* ts       = (const float*)d_in[7];
    // d_in[8] = current_ind (unused by reference)

    float* out  = (float*)d_out;                 // [2,3,32,32] = 6144 floats
    float* corr = out + 2*3*HH*WW;               // [2,1,49,256] = 25088 floats

    colorizer_fused<<<MAIN_BLOCKS + REG_BLOCKS, 256, 0, stream>>>(
        feats_r0, feats_r1, feats_t, q_r0, q_r1, rs1, ts, out, corr);
}